// Round 6
// baseline (283.437 us; speedup 1.0000x reference)
//
#include <hip/hip_runtime.h>
#include <hip/hip_bf16.h>

typedef __attribute__((ext_vector_type(8))) __bf16 bf16x8;
typedef __attribute__((ext_vector_type(4))) float f32x4;

#define N_SEQ   2048
#define N_BATCH 32
#define DIM_U   1024
#define NROWS   65536
#define MA_ELEMS ((size_t)NROWS * DIM_U) /* 67108864 */

__device__ __forceinline__ float tanh_fast(float x) {
    x = fminf(fmaxf(x, -15.f), 15.f);
    float e = __expf(2.f * x);
    return (e - 1.f) * __builtin_amdgcn_rcpf(e + 1.f);
}

// ---------------------------------------------------------------------------
// kernel 0: pack W (1024x512 f32) -> bf16, B-frag order.
// F = ((it*2+nh)*4+g)*256+col (it 0..31, g 0..3); elem j: k=it*32+g*8+j,
// c=nh*256+col. A B-fragment read (lane l: g=l>>4, col=wc*64+n*16+(l&15))
// is 16 consecutive 16B groups -> 256B coalesced per quarter-wave.
__global__ void wpack_kernel(const float* __restrict__ W, __bf16* __restrict__ Wp) {
    int F   = blockIdx.x * 256 + threadIdx.x;   // 0..65535
    int col = F & 255;
    int g   = (F >> 8) & 3;
    int nh  = (F >> 10) & 1;
    int it  = F >> 11;
    int k0  = it * 32 + g * 8;
    int c   = nh * 256 + col;
    bf16x8 o;
#pragma unroll
    for (int j = 0; j < 8; ++j) o[j] = (__bf16)W[(k0 + j) * 512 + c];
    *reinterpret_cast<bf16x8*>(Wp + (size_t)F * 8) = o;
}

// ---------------------------------------------------------------------------
// kernel 1: partial scores. WG = 128 rows x 256 cols, K=1024, BK=32, 32 iters.
// 512 thr = 8 waves (2M x 4N), wave 64x64 (acc 64 VGPR).
// A: LDS dbuf 2x8KB, XOR-swizzled [g][row^g][16B]; f32 loaded to regs 2 iters
// ahead, cvt+ds_write 1 iter ahead (T14). B: NO LDS - frag-coalesced register
// loads from L2-resident Wp (1MB), ping-pong bfA/bfB, 1 iter ahead.
// One raw barrier/iter with lgkmcnt(0) only (reg loads need no drain).
__global__ __launch_bounds__(512, 4) void score_gemm_kernel(
    const float* __restrict__ H, const __bf16* __restrict__ Wp,
    const float* __restrict__ Bb, const float* __restrict__ Uv,
    float* __restrict__ sp)
{
    __shared__ __align__(16) char lds[16384];
    const int tid  = threadIdx.x;
    const int lane = tid & 63;
    const int wid  = tid >> 6;     // 0..7
    const int c15  = lane & 15;
    const int hi   = lane >> 4;    // 0..3
    const int wr   = wid >> 2;     // 0..1 (M)
    const int wc   = wid & 3;      // 0..3 (N)

    // XCD-bijective swizzle (1024 % 8 == 0): (mt,nh) pairs adjacent on an XCD
    const int bid = blockIdx.x;
    const int L   = (bid & 7) * 128 + (bid >> 3);
    const int mt = L >> 1, nh = L & 1;
    const long rowbase = (long)mt * 128;

    // A staging: thread covers row=tid>>2, g=tid&3 (8 f32 -> 1 bf16x8)
    const int arow = tid >> 2, ag = tid & 3;
    const float* aglob = H + (rowbase + arow) * DIM_U + ag * 8;
    const int awoff = ag * 2048 + ((arow ^ ag) * 16);      // + db*8192

    // A frag read base (XOR-swizzled, conflict-free)
    const int abase0 = hi * 2048 + (wr * 64 + (c15 ^ hi)) * 16;   // + db*8192 + m*256

    // B frag pointer base: group (nh-half selected), lane part = hi*256 + ...
    const bf16x8* wpb = reinterpret_cast<const bf16x8*>(Wp) +
                        ((size_t)nh * 1024 + hi * 256 + wc * 64 + c15);

#define LOADB(bf_, it_) {                                                      \
        const bf16x8* bp_ = wpb + (size_t)(it_) * 2048;                        \
        _Pragma("unroll")                                                      \
        for (int n_ = 0; n_ < 4; ++n_) bf_[n_] = bp_[n_ * 16]; }

#define LOADA(La_, Lb_, it_) {                                                 \
        const float* p_ = aglob + (it_) * 32;                                  \
        La_ = *reinterpret_cast<const f32x4*>(p_);                             \
        Lb_ = *reinterpret_cast<const f32x4*>(p_ + 4); }

#define CVTW(La_, Lb_, db_) {                                                  \
        bf16x8 pk_ = {(__bf16)La_.x, (__bf16)La_.y, (__bf16)La_.z,             \
                      (__bf16)La_.w, (__bf16)Lb_.x, (__bf16)Lb_.y,             \
                      (__bf16)Lb_.z, (__bf16)Lb_.w};                           \
        *reinterpret_cast<bf16x8*>(lds + (db_) * 8192 + awoff) = pk_; }

#define COMPUTE(db_, bf_) {                                                    \
        bf16x8 af[4];                                                          \
        _Pragma("unroll")                                                      \
        for (int m_ = 0; m_ < 4; ++m_)                                         \
            af[m_] = *reinterpret_cast<const bf16x8*>(                         \
                lds + (db_) * 8192 + abase0 + m_ * 256);                       \
        __builtin_amdgcn_s_setprio(1);                                         \
        _Pragma("unroll")                                                      \
        for (int m_ = 0; m_ < 4; ++m_) {                                       \
            _Pragma("unroll")                                                  \
            for (int n_ = 0; n_ < 4; ++n_)                                     \
                acc[m_][n_] = __builtin_amdgcn_mfma_f32_16x16x32_bf16(         \
                    af[m_], bf_[n_], acc[m_][n_], 0, 0, 0);                    \
        }                                                                      \
        __builtin_amdgcn_s_setprio(0); }

#define BAR { asm volatile("s_waitcnt lgkmcnt(0)" ::: "memory");               \
              __builtin_amdgcn_s_barrier(); }

    f32x4 acc[4][4];
#pragma unroll
    for (int m = 0; m < 4; ++m)
#pragma unroll
        for (int n = 0; n < 4; ++n) acc[m][n] = f32x4{0.f, 0.f, 0.f, 0.f};

    f32x4 L0a, L0b, L1a, L1b;
    bf16x8 bfA[4], bfB[4];

    // ---- prologue: A(0) -> buf0; B(0) -> bfA; A(1) in flight
    LOADA(L0a, L0b, 0);
    CVTW(L0a, L0b, 0);                   // compiler waits on L0 here
    LOADB(bfA, 0);
    __builtin_amdgcn_sched_barrier(0);
    LOADA(L1a, L1b, 1);
    __builtin_amdgcn_sched_barrier(0);
    BAR;                                 // buf0 A visible to all waves

    // ---- main loop: 2-iter unrolled ping-pong, peeled 30/31
    for (int tt = 0; tt < 15; ++tt) {
        const int t0 = 2 * tt;
        // even iter t0: read buf0 + bfA; prefetch B(t0+1), A(t0+2)
        LOADB(bfB, t0 + 1);
        LOADA(L0a, L0b, t0 + 2);
        __builtin_amdgcn_sched_barrier(0);
        COMPUTE(0, bfA);
        CVTW(L1a, L1b, 1);               // A(t0+1) -> buf1
        BAR;
        // odd iter t0+1: read buf1 + bfB; prefetch B(t0+2), A(t0+3)
        LOADB(bfA, t0 + 2);
        LOADA(L1a, L1b, t0 + 3);
        __builtin_amdgcn_sched_barrier(0);
        COMPUTE(1, bfB);
        CVTW(L0a, L0b, 0);               // A(t0+2) -> buf0
        BAR;
    }
    // iter 30 (buf0, bfA holds B(30))
    LOADB(bfB, 31);
    COMPUTE(0, bfA);
    CVTW(L1a, L1b, 1);                   // A(31) -> buf1
    BAR;
    // iter 31 (buf1, bfB)
    COMPUTE(1, bfB);

    // ---- epilogue: tanh(acc + bias)*U, reduce over the WG's 256 cols
    float bias[4], uu[4];
#pragma unroll
    for (int n = 0; n < 4; ++n) {
        int col = nh * 256 + wc * 64 + n * 16 + c15;
        bias[n] = Bb[col];
        uu[n]   = Uv[col];
    }
    float* partial = reinterpret_cast<float*>(lds);  // [4 wc][128 rows]
#pragma unroll
    for (int m = 0; m < 4; ++m) {
        float pr[4];
#pragma unroll
        for (int r = 0; r < 4; ++r) pr[r] = 0.f;
#pragma unroll
        for (int n = 0; n < 4; ++n)
#pragma unroll
            for (int r = 0; r < 4; ++r)
                pr[r] += tanh_fast(acc[m][n][r] + bias[n]) * uu[n];
#pragma unroll
        for (int r = 0; r < 4; ++r) {
            float v = pr[r];
            v += __shfl_xor(v, 1); v += __shfl_xor(v, 2);
            v += __shfl_xor(v, 4); v += __shfl_xor(v, 8);
            if (c15 == 0)
                partial[wc * 128 + wr * 64 + m * 16 + hi * 4 + r] = v;
        }
    }
    __syncthreads();
    if (tid < 128) {
        float sc = (partial[tid] + partial[128 + tid]) +
                   (partial[256 + tid] + partial[384 + tid]);
        sp[(size_t)nh * NROWS + rowbase + tid] = sc;
    }
}

// ---------------------------------------------------------------------------
// kernel 2: per-batch softmax over n=2048 (scores = sum of 2 N-partials)
__global__ void softmax_kernel(const float* __restrict__ sp, float* __restrict__ VU) {
    __shared__ float red[8];
    const int b = blockIdx.x, tid = threadIdx.x;
    const int lane = tid & 63, wid = tid >> 6;
    float v[8];
    float mx = -3.0e38f;
#pragma unroll
    for (int j = 0; j < 8; ++j) {
        int x = b * N_SEQ + tid + j * 256;
        v[j] = sp[x] + sp[NROWS + x];
        mx = fmaxf(mx, v[j]);
    }
#pragma unroll
    for (int off = 1; off < 64; off <<= 1) mx = fmaxf(mx, __shfl_xor(mx, off));
    if (lane == 0) red[wid] = mx;
    __syncthreads();
    mx = fmaxf(fmaxf(red[0], red[1]), fmaxf(red[2], red[3]));
    float e[8], sum = 0.f;
#pragma unroll
    for (int j = 0; j < 8; ++j) { e[j] = __expf(v[j] - mx); sum += e[j]; }
#pragma unroll
    for (int off = 1; off < 64; off <<= 1) sum += __shfl_xor(sum, off);
    if (lane == 0) red[4 + wid] = sum;
    __syncthreads();
    float total = (red[4] + red[5]) + (red[6] + red[7]);
    float rinv = 1.f / total;
#pragma unroll
    for (int j = 0; j < 8; ++j) VU[b * N_SEQ + tid + j * 256] = e[j] * rinv;
}

// ---------------------------------------------------------------------------
// kernel 3: Ma = H * VU (broadcast over u); nontemporal stores (write-once)
__global__ void ma_kernel(const float* __restrict__ H, const float* __restrict__ VU,
                          float* __restrict__ Ma) {
    const int stride = gridDim.x * blockDim.x;
    const int n4 = (int)(MA_ELEMS / 4);
    for (int i4 = blockIdx.x * blockDim.x + threadIdx.x; i4 < n4; i4 += stride) {
        float sc = VU[i4 >> 8];                         // 256 float4 per row
        f32x4 h = reinterpret_cast<const f32x4*>(H)[i4];
        __builtin_nontemporal_store(h * sc, reinterpret_cast<f32x4*>(Ma) + i4);
    }
}

// ---------------------------------------------------------------------------
extern "C" void kernel_launch(void* const* d_in, const int* in_sizes, int n_in,
                              void* d_out, int out_size, void* d_ws, size_t ws_size,
                              hipStream_t stream) {
    const float* H  = (const float*)d_in[0];
    const float* W  = (const float*)d_in[1];
    const float* Bb = (const float*)d_in[2];
    const float* Uv = (const float*)d_in[3];

    float* out = (float*)d_out;
    float* Ma  = out;                          // 67108864 floats
    float* VU  = out + MA_ELEMS;               // 65536 floats
    // scratch inside the Ma region (ma_kernel overwrites it all at the end):
    float*  sp = out;                          // 2 x 65536 partial scores
    __bf16* Wp = (__bf16*)(out + 131072);      // 524288 bf16 (1MB)

    wpack_kernel<<<256, 256, 0, stream>>>(W, Wp);
    score_gemm_kernel<<<1024, 512, 0, stream>>>(H, Wp, Bb, Uv, sp);
    softmax_kernel<<<N_BATCH, 256, 0, stream>>>(sp, VU);
    ma_kernel<<<2048, 256, 0, stream>>>(H, VU, Ma);
}

// Round 7
// 176.297 us; speedup vs baseline: 1.6077x; 1.6077x over previous
//
#include <hip/hip_runtime.h>
#include <hip/hip_bf16.h>

typedef __attribute__((ext_vector_type(8))) __bf16 bf16x8;
typedef __attribute__((ext_vector_type(4))) float f32x4;

#define N_SEQ   2048
#define N_BATCH 32
#define DIM_U   1024
#define NROWS   65536
#define MA_ELEMS ((size_t)NROWS * DIM_U) /* 67108864 */

__device__ __forceinline__ float tanh_fast(float x) {
    x = fminf(fmaxf(x, -15.f), 15.f);
    float e = __expf(2.f * x);
    return (e - 1.f) * __builtin_amdgcn_rcpf(e + 1.f);
}

// ---------------------------------------------------------------------------
// kernel 0: pack W (1024x512 f32) -> bf16, B-frag order.
// Group F = ((it*2+nh)*4+g)*256+col (it 0..31, g 0..3, col 0..255);
// elem j: k=it*32+g*8+j, c=nh*256+col. A B-fragment read (lane l: g=l>>4,
// col=wc*64+n*16+(l&15)) is 16 consecutive 16B groups -> 256B / quarter-wave.
__global__ void wpack_kernel(const float* __restrict__ W, __bf16* __restrict__ Wp) {
    int F   = blockIdx.x * 256 + threadIdx.x;   // 0..65535
    int col = F & 255;
    int g   = (F >> 8) & 3;
    int nh  = (F >> 10) & 1;
    int it  = F >> 11;
    int k0  = it * 32 + g * 8;
    int c   = nh * 256 + col;
    bf16x8 o;
#pragma unroll
    for (int j = 0; j < 8; ++j) o[j] = (__bf16)W[(k0 + j) * 512 + c];
    *reinterpret_cast<bf16x8*>(Wp + (size_t)F * 8) = o;
}

// ---------------------------------------------------------------------------
// kernel 1: partial scores. WG = 128 rows x 256 cols, K=1024, BK=32, 32 iters.
// 512 thr = 8 waves (2M x 4N), wave 64x64 (acc 64 in accum half).
// A: LDS dbuf 2x8KB XOR-swizzled, f32->reg 1 iter ahead, cvt+ds_write end of
// prev iter. B: NO LDS - frag-coalesced reg loads from L2-resident Wp (1MB),
// ping-pong bfA/bfB. One raw barrier/iter, lgkmcnt(0) only (vmcnt free-runs).
// Register budget (launch_bounds(512,4) => 128 total): acc 64 + bf 32 +
// af-pair 8 + L 8 + addr ~8 = ~120.  [R6 lesson: 140 > 128 spilled 140MB.]
__global__ __launch_bounds__(512, 4) void score_gemm_kernel(
    const float* __restrict__ H, const __bf16* __restrict__ Wp,
    const float* __restrict__ Bb, const float* __restrict__ Uv,
    float* __restrict__ sp)
{
    __shared__ __align__(16) char lds[16384];
    const int tid  = threadIdx.x;
    const int lane = tid & 63;
    const int wid  = tid >> 6;     // 0..7
    const int c15  = lane & 15;
    const int hi   = lane >> 4;    // 0..3
    const int wr   = wid >> 2;     // 0..1 (M)
    const int wc   = wid & 3;      // 0..3 (N)

    // XCD-bijective swizzle (1024 % 8 == 0): (mt,nh) pairs adjacent on an XCD
    const int bid = blockIdx.x;
    const int L   = (bid & 7) * 128 + (bid >> 3);
    const int mt = L >> 1, nh = L & 1;
    const long rowbase = (long)mt * 128;

    // A staging: thread covers row=tid>>2, g=tid&3 (8 f32 -> 1 bf16x8)
    const int arow = tid >> 2, ag = tid & 3;
    const float* aglob = H + (rowbase + arow) * DIM_U + ag * 8;
    const int awoff = ag * 2048 + ((arow ^ ag) * 16);      // + db*8192

    // A frag read base (XOR-swizzled, conflict-free)
    const int abase0 = hi * 2048 + (wr * 64 + (c15 ^ hi)) * 16;   // + db*8192 + m*256

    // B frag pointer base (16B-group units)
    const bf16x8* wpb = reinterpret_cast<const bf16x8*>(Wp) +
                        ((size_t)nh * 1024 + hi * 256 + wc * 64 + c15);

#define LOADB(bf_, it_) {                                                      \
        const bf16x8* bp_ = wpb + (size_t)(it_) * 2048;                        \
        _Pragma("unroll")                                                      \
        for (int n_ = 0; n_ < 4; ++n_) bf_[n_] = bp_[n_ * 16]; }

#define LOADA(La_, Lb_, it_) {                                                 \
        const float* p_ = aglob + (it_) * 32;                                  \
        La_ = *reinterpret_cast<const f32x4*>(p_);                             \
        Lb_ = *reinterpret_cast<const f32x4*>(p_ + 4); }

#define CVTW(La_, Lb_, db_) {                                                  \
        bf16x8 pk_ = {(__bf16)La_.x, (__bf16)La_.y, (__bf16)La_.z,             \
                      (__bf16)La_.w, (__bf16)Lb_.x, (__bf16)Lb_.y,             \
                      (__bf16)Lb_.z, (__bf16)Lb_.w};                           \
        *reinterpret_cast<bf16x8*>(lds + (db_) * 8192 + awoff) = pk_; }

#define MFMA_PAIR(m0_, a0_, a1_, bf_)                                          \
        _Pragma("unroll")                                                      \
        for (int n_ = 0; n_ < 4; ++n_) {                                       \
            acc[(m0_)][n_] = __builtin_amdgcn_mfma_f32_16x16x32_bf16(          \
                a0_, bf_[n_], acc[(m0_)][n_], 0, 0, 0);                        \
            acc[(m0_) + 1][n_] = __builtin_amdgcn_mfma_f32_16x16x32_bf16(      \
                a1_, bf_[n_], acc[(m0_) + 1][n_], 0, 0, 0);                    \
        }

#define COMPUTE(db_, bf_) {                                                    \
        bf16x8 a0_, a1_;                                                       \
        a0_ = *reinterpret_cast<const bf16x8*>(lds + (db_) * 8192 + abase0);   \
        a1_ = *reinterpret_cast<const bf16x8*>(lds + (db_) * 8192 + abase0 + 256); \
        __builtin_amdgcn_s_setprio(1);                                         \
        MFMA_PAIR(0, a0_, a1_, bf_);                                           \
        __builtin_amdgcn_s_setprio(0);                                         \
        a0_ = *reinterpret_cast<const bf16x8*>(lds + (db_) * 8192 + abase0 + 512); \
        a1_ = *reinterpret_cast<const bf16x8*>(lds + (db_) * 8192 + abase0 + 768); \
        __builtin_amdgcn_s_setprio(1);                                         \
        MFMA_PAIR(2, a0_, a1_, bf_);                                           \
        __builtin_amdgcn_s_setprio(0); }

#define BAR { asm volatile("s_waitcnt lgkmcnt(0)" ::: "memory");               \
              __builtin_amdgcn_s_barrier(); }

    f32x4 acc[4][4];
#pragma unroll
    for (int m = 0; m < 4; ++m)
#pragma unroll
        for (int n = 0; n < 4; ++n) acc[m][n] = f32x4{0.f, 0.f, 0.f, 0.f};

    f32x4 L1a, L1b;
    bf16x8 bfA[4], bfB[4];

    // ---- prologue: A(0) -> buf0; B(0) -> bfA
    LOADA(L1a, L1b, 0);
    CVTW(L1a, L1b, 0);                   // compiler waits on the loads here
    LOADB(bfA, 0);
    BAR;                                 // buf0 visible to all waves

    // ---- main loop: 2-iter unrolled ping-pong, iters 30/31 peeled
    for (int tt = 0; tt < 15; ++tt) {
        const int t0 = 2 * tt;
        // even iter t0: read buf0 + bfA; prefetch B(t0+1), A(t0+1)
        LOADB(bfB, t0 + 1);
        LOADA(L1a, L1b, t0 + 1);
        __builtin_amdgcn_sched_barrier(0);
        COMPUTE(0, bfA);
        __builtin_amdgcn_sched_barrier(0);
        CVTW(L1a, L1b, 1);               // A(t0+1) -> buf1
        BAR;
        // odd iter t0+1: read buf1 + bfB; prefetch B(t0+2), A(t0+2)
        LOADB(bfA, t0 + 2);
        LOADA(L1a, L1b, t0 + 2);
        __builtin_amdgcn_sched_barrier(0);
        COMPUTE(1, bfB);
        __builtin_amdgcn_sched_barrier(0);
        CVTW(L1a, L1b, 0);               // A(t0+2) -> buf0
        BAR;
    }
    // iter 30 (buf0, bfA)
    LOADB(bfB, 31);
    LOADA(L1a, L1b, 31);
    __builtin_amdgcn_sched_barrier(0);
    COMPUTE(0, bfA);
    __builtin_amdgcn_sched_barrier(0);
    CVTW(L1a, L1b, 1);                   // A(31) -> buf1
    BAR;
    // iter 31 (buf1, bfB)
    COMPUTE(1, bfB);

    // ---- epilogue: tanh(acc + bias)*U, reduce over the WG's 256 cols
    float bias[4], uu[4];
#pragma unroll
    for (int n = 0; n < 4; ++n) {
        int col = nh * 256 + wc * 64 + n * 16 + c15;
        bias[n] = Bb[col];
        uu[n]   = Uv[col];
    }
    float* partial = reinterpret_cast<float*>(lds);  // [4 wc][128 rows] (buf0)
#pragma unroll
    for (int m = 0; m < 4; ++m) {
        float pr[4];
#pragma unroll
        for (int r = 0; r < 4; ++r) pr[r] = 0.f;
#pragma unroll
        for (int n = 0; n < 4; ++n)
#pragma unroll
            for (int r = 0; r < 4; ++r)
                pr[r] += tanh_fast(acc[m][n][r] + bias[n]) * uu[n];
#pragma unroll
        for (int r = 0; r < 4; ++r) {
            float v = pr[r];
            v += __shfl_xor(v, 1); v += __shfl_xor(v, 2);
            v += __shfl_xor(v, 4); v += __shfl_xor(v, 8);
            if (c15 == 0)
                partial[wc * 128 + wr * 64 + m * 16 + hi * 4 + r] = v;
        }
    }
    __syncthreads();
    if (tid < 128) {
        float sc = (partial[tid] + partial[128 + tid]) +
                   (partial[256 + tid] + partial[384 + tid]);
        sp[(size_t)nh * NROWS + rowbase + tid] = sc;
    }
}

// ---------------------------------------------------------------------------
// kernel 2: per-batch softmax over n=2048 (scores = sum of 2 N-partials)
__global__ void softmax_kernel(const float* __restrict__ sp, float* __restrict__ VU) {
    __shared__ float red[8];
    const int b = blockIdx.x, tid = threadIdx.x;
    const int lane = tid & 63, wid = tid >> 6;
    float v[8];
    float mx = -3.0e38f;
#pragma unroll
    for (int j = 0; j < 8; ++j) {
        int x = b * N_SEQ + tid + j * 256;
        v[j] = sp[x] + sp[NROWS + x];
        mx = fmaxf(mx, v[j]);
    }
#pragma unroll
    for (int off = 1; off < 64; off <<= 1) mx = fmaxf(mx, __shfl_xor(mx, off));
    if (lane == 0) red[wid] = mx;
    __syncthreads();
    mx = fmaxf(fmaxf(red[0], red[1]), fmaxf(red[2], red[3]));
    float e[8], sum = 0.f;
#pragma unroll
    for (int j = 0; j < 8; ++j) { e[j] = __expf(v[j] - mx); sum += e[j]; }
#pragma unroll
    for (int off = 1; off < 64; off <<= 1) sum += __shfl_xor(sum, off);
    if (lane == 0) red[4 + wid] = sum;
    __syncthreads();
    float total = (red[4] + red[5]) + (red[6] + red[7]);
    float rinv = 1.f / total;
#pragma unroll
    for (int j = 0; j < 8; ++j) VU[b * N_SEQ + tid + j * 256] = e[j] * rinv;
}

// ---------------------------------------------------------------------------
// kernel 3: Ma = H * VU (broadcast over u); nontemporal stores (write-once)
__global__ void ma_kernel(const float* __restrict__ H, const float* __restrict__ VU,
                          float* __restrict__ Ma) {
    const int stride = gridDim.x * blockDim.x;
    const int n4 = (int)(MA_ELEMS / 4);
    for (int i4 = blockIdx.x * blockDim.x + threadIdx.x; i4 < n4; i4 += stride) {
        float sc = VU[i4 >> 8];                         // 256 float4 per row
        f32x4 h = reinterpret_cast<const f32x4*>(H)[i4];
        __builtin_nontemporal_store(h * sc, reinterpret_cast<f32x4*>(Ma) + i4);
    }
}

// ---------------------------------------------------------------------------
extern "C" void kernel_launch(void* const* d_in, const int* in_sizes, int n_in,
                              void* d_out, int out_size, void* d_ws, size_t ws_size,
                              hipStream_t stream) {
    const float* H  = (const float*)d_in[0];
    const float* W  = (const float*)d_in[1];
    const float* Bb = (const float*)d_in[2];
    const float* Uv = (const float*)d_in[3];

    float* out = (float*)d_out;
    float* Ma  = out;                          // 67108864 floats
    float* VU  = out + MA_ELEMS;               // 65536 floats
    // scratch inside the Ma region (ma_kernel overwrites it all at the end):
    float*  sp = out;                          // 2 x 65536 partial scores
    __bf16* Wp = (__bf16*)(out + 131072);      // 524288 bf16 (1MB)

    wpack_kernel<<<256, 256, 0, stream>>>(W, Wp);
    score_gemm_kernel<<<1024, 512, 0, stream>>>(H, Wp, Bb, Uv, sp);
    softmax_kernel<<<N_BATCH, 256, 0, stream>>>(sp, VU);
    ma_kernel<<<2048, 256, 0, stream>>>(H, VU, Ma);
}

// Round 8
// 163.687 us; speedup vs baseline: 1.7316x; 1.0770x over previous
//
#include <hip/hip_runtime.h>
#include <hip/hip_bf16.h>

typedef __attribute__((ext_vector_type(8))) __bf16 bf16x8;
typedef __attribute__((ext_vector_type(4))) float f32x4;

#define N_SEQ   2048
#define N_BATCH 32
#define DIM_U   1024
#define NROWS   65536
#define MA_ELEMS ((size_t)NROWS * DIM_U) /* 67108864 */

__device__ __forceinline__ float tanh_fast(float x) {
    x = fminf(fmaxf(x, -15.f), 15.f);
    float e = __expf(2.f * x);
    return (e - 1.f) * __builtin_amdgcn_rcpf(e + 1.f);
}

// ---------------------------------------------------------------------------
// kernel 0: pack W (1024x512 f32) -> bf16, B-stage order.
// F = ((it*2+nh)*4+g)*256+col (it 0..31, g 0..3); elem j: k=it*32+g*8+j,
// c=nh*256+col. Chunk (it,nh) = 1024 groups = 16KB = one LDS B-slab
// [g][col256][16B], global order == LDS linear order (gload_lds identity).
__global__ void wpack_kernel(const float* __restrict__ W, __bf16* __restrict__ Wp) {
    int F   = blockIdx.x * 256 + threadIdx.x;   // 0..65535
    int col = F & 255;
    int g   = (F >> 8) & 3;
    int nh  = (F >> 10) & 1;
    int it  = F >> 11;
    int k0  = it * 32 + g * 8;
    int c   = nh * 256 + col;
    bf16x8 o;
#pragma unroll
    for (int j = 0; j < 8; ++j) o[j] = (__bf16)W[(k0 + j) * 512 + c];
    *reinterpret_cast<bf16x8*>(Wp + (size_t)F * 8) = o;
}

// ---------------------------------------------------------------------------
// kernel 1 (R5-proven): partial scores. WG = 128 rows x 256 cols, BK=32,
// 32 iters. 8 waves (2M x 4N), wave 64x64. LDS 48KB: A dbuf 2x8KB XOR-swz,
// B dbuf 2x16KB via gload_lds. One barrier/iter, counted vmcnt(2).
__global__ __launch_bounds__(512, 4) void score_gemm_kernel(
    const float* __restrict__ H, const __bf16* __restrict__ Wp,
    const float* __restrict__ Bb, const float* __restrict__ Uv,
    float* __restrict__ sp)
{
    __shared__ __align__(16) char lds[49152];
    const int tid  = threadIdx.x;
    const int lane = tid & 63;
    const int wid  = tid >> 6;     // 0..7
    const int c15  = lane & 15;
    const int hi   = lane >> 4;    // 0..3
    const int wr   = wid >> 2;     // 0..1 (M)
    const int wc   = wid & 3;      // 0..3 (N)

    // XCD-bijective swizzle: segment s = bid&7 covers H rows [s*8192,(s+1)*8192)
    const int bid = blockIdx.x;
    const int L   = (bid & 7) * 128 + (bid >> 3);
    const int mt = L >> 1, nh = L & 1;
    const long rowbase = (long)mt * 128;

    // A staging: thread covers row=tid>>2, g=tid&3 (8 f32 -> 1 bf16x8)
    const int arow = tid >> 2, ag = tid & 3;
    const float* aglob = H + (rowbase + arow) * DIM_U + ag * 8;
    const int awoff = ag * 2048 + ((arow ^ ag) * 16);      // + db*8192

    // frag read bases
    const int abase0 = hi * 2048 + (wr * 64 + (c15 ^ hi)) * 16;   // + db*8192 + m*256
    const int bbase0 = 16384 + hi * 4096 + (wc * 64 + c15) * 16;  // + db*16384 + n*256

#define GLD(srcp, dstoff)                                                      \
    __builtin_amdgcn_global_load_lds(                                          \
        (const __attribute__((address_space(1))) void*)(const void*)(srcp),    \
        (__attribute__((address_space(3))) void*)(void*)(lds + (dstoff)), 16, 0, 0)

#define STAGE_B(it_, db_) {                                                    \
        const __bf16* bg_ = Wp + (((size_t)(it_) * 2 + nh) * 1024) * 8;        \
        GLD(bg_ + (size_t)tid * 8,         16384 + (db_) * 16384 + tid * 16);  \
        GLD(bg_ + ((size_t)tid + 512) * 8, 16384 + (db_) * 16384 + 8192 + tid * 16); }

#define LOADA(La_, Lb_, it_) {                                                 \
        const float* p_ = aglob + (it_) * 32;                                  \
        La_ = *reinterpret_cast<const f32x4*>(p_);                             \
        Lb_ = *reinterpret_cast<const f32x4*>(p_ + 4); }

#define CVTW(La_, Lb_, db_) {                                                  \
        bf16x8 pk_ = {(__bf16)La_.x, (__bf16)La_.y, (__bf16)La_.z,             \
                      (__bf16)La_.w, (__bf16)Lb_.x, (__bf16)Lb_.y,             \
                      (__bf16)Lb_.z, (__bf16)Lb_.w};                           \
        *reinterpret_cast<bf16x8*>(lds + (db_) * 8192 + awoff) = pk_; }

#define COMPUTE(db_) {                                                         \
        bf16x8 af[4], bf[4];                                                   \
        _Pragma("unroll")                                                      \
        for (int m = 0; m < 4; ++m)                                            \
            af[m] = *reinterpret_cast<const bf16x8*>(                          \
                lds + (db_) * 8192 + abase0 + m * 256);                        \
        _Pragma("unroll")                                                      \
        for (int n = 0; n < 4; ++n)                                            \
            bf[n] = *reinterpret_cast<const bf16x8*>(                          \
                lds + (db_) * 16384 + bbase0 + n * 256);                       \
        __builtin_amdgcn_s_setprio(1);                                         \
        _Pragma("unroll")                                                      \
        for (int m = 0; m < 4; ++m) {                                          \
            _Pragma("unroll")                                                  \
            for (int n = 0; n < 4; ++n)                                        \
                acc[m][n] = __builtin_amdgcn_mfma_f32_16x16x32_bf16(           \
                    af[m], bf[n], acc[m][n], 0, 0, 0);                         \
        }                                                                      \
        __builtin_amdgcn_s_setprio(0); }

#define WAITBAR2 { asm volatile("s_waitcnt vmcnt(2) lgkmcnt(0)" ::: "memory"); \
                   __builtin_amdgcn_s_barrier(); }
#define WAITBAR0 { asm volatile("s_waitcnt vmcnt(0) lgkmcnt(0)" ::: "memory"); \
                   __builtin_amdgcn_s_barrier(); }

    f32x4 acc[4][4];
#pragma unroll
    for (int m = 0; m < 4; ++m)
#pragma unroll
        for (int n = 0; n < 4; ++n) acc[m][n] = f32x4{0.f, 0.f, 0.f, 0.f};

    f32x4 L0a, L0b, L1a, L1b;

    // ---- prologue: A(0)+B(0) -> buf0; A(1) in flight
    LOADA(L0a, L0b, 0);
    CVTW(L0a, L0b, 0);                  // compiler waits on L0 here
    STAGE_B(0, 0);
    __builtin_amdgcn_sched_barrier(0);
    LOADA(L1a, L1b, 1);
    __builtin_amdgcn_sched_barrier(0);
    WAITBAR2;                            // B(0) landed; A(1) flying

    // ---- main loop: iters 0..29 (pairs), peeled 30/31
    for (int tt = 0; tt < 15; ++tt) {
        const int t0 = 2 * tt;
        // even iter t0: read buf0, stage buf1
        STAGE_B(t0 + 1, 1);
        __builtin_amdgcn_sched_barrier(0);
        LOADA(L0a, L0b, t0 + 2);
        __builtin_amdgcn_sched_barrier(0);
        COMPUTE(0);
        CVTW(L1a, L1b, 1);               // A(t0+1)
        WAITBAR2;
        // odd iter t0+1: read buf1, stage buf0
        STAGE_B(t0 + 2, 0);
        __builtin_amdgcn_sched_barrier(0);
        LOADA(L1a, L1b, t0 + 3);
        __builtin_amdgcn_sched_barrier(0);
        COMPUTE(1);
        CVTW(L0a, L0b, 0);               // A(t0+2)
        WAITBAR2;
    }
    // iter 30 (reads buf0, stages buf1)
    STAGE_B(31, 1);
    COMPUTE(0);
    CVTW(L1a, L1b, 1);                   // A(31)
    WAITBAR0;
    // iter 31 (reads buf1)
    COMPUTE(1);

    // ---- epilogue: tanh(acc + bias)*U, reduce over the WG's 256 cols
    float bias[4], uu[4];
#pragma unroll
    for (int n = 0; n < 4; ++n) {
        int col = nh * 256 + wc * 64 + n * 16 + c15;
        bias[n] = Bb[col];
        uu[n]   = Uv[col];
    }
    float* partial = reinterpret_cast<float*>(lds);  // [4 wc][128 rows]
#pragma unroll
    for (int m = 0; m < 4; ++m) {
        float pr[4];
#pragma unroll
        for (int r = 0; r < 4; ++r) pr[r] = 0.f;
#pragma unroll
        for (int n = 0; n < 4; ++n)
#pragma unroll
            for (int r = 0; r < 4; ++r)
                pr[r] += tanh_fast(acc[m][n][r] + bias[n]) * uu[n];
#pragma unroll
        for (int r = 0; r < 4; ++r) {
            float v = pr[r];
            v += __shfl_xor(v, 1); v += __shfl_xor(v, 2);
            v += __shfl_xor(v, 4); v += __shfl_xor(v, 8);
            if (c15 == 0)
                partial[wc * 128 + wr * 64 + m * 16 + hi * 4 + r] = v;
        }
    }
    __syncthreads();
    if (tid < 128) {
        float sc = (partial[tid] + partial[128 + tid]) +
                   (partial[256 + tid] + partial[384 + tid]);
        sp[(size_t)nh * NROWS + rowbase + tid] = sc;
    }
}

// ---------------------------------------------------------------------------
// kernel 2: per-batch softmax over n=2048 (scores = sum of 2 N-partials)
__global__ void softmax_kernel(const float* __restrict__ sp, float* __restrict__ VU) {
    __shared__ float red[8];
    const int b = blockIdx.x, tid = threadIdx.x;
    const int lane = tid & 63, wid = tid >> 6;
    float v[8];
    float mx = -3.0e38f;
#pragma unroll
    for (int j = 0; j < 8; ++j) {
        int x = b * N_SEQ + tid + j * 256;
        v[j] = sp[x] + sp[NROWS + x];
        mx = fmaxf(mx, v[j]);
    }
#pragma unroll
    for (int off = 1; off < 64; off <<= 1) mx = fmaxf(mx, __shfl_xor(mx, off));
    if (lane == 0) red[wid] = mx;
    __syncthreads();
    mx = fmaxf(fmaxf(red[0], red[1]), fmaxf(red[2], red[3]));
    float e[8], sum = 0.f;
#pragma unroll
    for (int j = 0; j < 8; ++j) { e[j] = __expf(v[j] - mx); sum += e[j]; }
#pragma unroll
    for (int off = 1; off < 64; off <<= 1) sum += __shfl_xor(sum, off);
    if (lane == 0) red[4 + wid] = sum;
    __syncthreads();
    float total = (red[4] + red[5]) + (red[6] + red[7]);
    float rinv = 1.f / total;
#pragma unroll
    for (int j = 0; j < 8; ++j) VU[b * N_SEQ + tid + j * 256] = e[j] * rinv;
}

// ---------------------------------------------------------------------------
// kernel 3: Ma = H * VU, L3-locality ordered. The GEMM reads H as 8 XCD
// segments (segment s = rows [s*8192,(s+1)*8192)), each forward in time.
// ma processes each segment BACKWARD (block b: s=b&7, chunk 255-(b>>3), 32
// rows), so its reads start where the GEMM's reads ended (freshest in L3),
// and the next replay's forward GEMM starts where ma ended. NT stores keep
// the Ma write stream from evicting H.
__global__ void ma_kernel(const float* __restrict__ H, const float* __restrict__ VU,
                          float* __restrict__ Ma) {
    const int b = blockIdx.x;                    // 0..2047
    const int s = b & 7, j = b >> 3;             // segment, chunk-in-segment
    const long row0 = (long)s * 8192 + (long)(255 - j) * 32;
    const int tid = threadIdx.x;                 // 256 thr: one f32x4 per row
    const float* h = H + row0 * DIM_U;
    float*       o = Ma + row0 * DIM_U;
#pragma unroll 4
    for (int r = 0; r < 32; ++r) {
        float sc = VU[row0 + r];                 // uniform -> s_load
        f32x4 hv = reinterpret_cast<const f32x4*>(h + (size_t)r * DIM_U)[tid];
        __builtin_nontemporal_store(hv * sc,
            reinterpret_cast<f32x4*>(o + (size_t)r * DIM_U) + tid);
    }
}

// ---------------------------------------------------------------------------
extern "C" void kernel_launch(void* const* d_in, const int* in_sizes, int n_in,
                              void* d_out, int out_size, void* d_ws, size_t ws_size,
                              hipStream_t stream) {
    const float* H  = (const float*)d_in[0];
    const float* W  = (const float*)d_in[1];
    const float* Bb = (const float*)d_in[2];
    const float* Uv = (const float*)d_in[3];

    float* out = (float*)d_out;
    float* Ma  = out;                          // 67108864 floats
    float* VU  = out + MA_ELEMS;               // 65536 floats
    // scratch inside the Ma region (ma_kernel overwrites it all at the end):
    float*  sp = out;                          // 2 x 65536 partial scores
    __bf16* Wp = (__bf16*)(out + 131072);      // 524288 bf16 (1MB)

    wpack_kernel<<<256, 256, 0, stream>>>(W, Wp);
    score_gemm_kernel<<<1024, 512, 0, stream>>>(H, Wp, Bb, Uv, sp);
    softmax_kernel<<<N_BATCH, 256, 0, stream>>>(sp, VU);
    ma_kernel<<<2048, 256, 0, stream>>>(H, VU, Ma);
}